// Round 1
// baseline (528.000 us; speedup 1.0000x reference)
//
#include <hip/hip_runtime.h>
#include <math.h>

#define N_NODES 50000
#define FIN 512
#define NE 800000
#define ETOT 850000   // NE + N_NODES self loops
#define F1 128        // H1*C1
#define H1 8
#define F2 40

// ---------------- CSR build ----------------

__global__ __launch_bounds__(256) void k_hist(const int* __restrict__ dst, int* __restrict__ deg){
  int i = blockIdx.x*256 + threadIdx.x;
  if(i < ETOT){
    int d = (i < NE) ? dst[i] : (i - NE);
    atomicAdd(&deg[d], 1);
  }
}

__global__ __launch_bounds__(256) void k_scan1(const int* __restrict__ deg, int* __restrict__ row_ptr,
                                               int* __restrict__ partials){
  __shared__ int sm[256];
  int t = threadIdx.x;
  int i = blockIdx.x*256 + t;
  int v = (i < N_NODES) ? deg[i] : 0;
  sm[t] = v;
  __syncthreads();
  for(int off=1; off<256; off<<=1){
    int x = (t >= off) ? sm[t-off] : 0;
    __syncthreads();
    sm[t] += x;
    __syncthreads();
  }
  if(i < N_NODES) row_ptr[i] = sm[t] - v;   // exclusive within block
  if(t == 255) partials[blockIdx.x] = sm[255];
}

__global__ __launch_bounds__(256) void k_scan2(int* __restrict__ partials, int nblocks){
  __shared__ int sm[256];
  int t = threadIdx.x;
  int v = (t < nblocks) ? partials[t] : 0;
  sm[t] = v;
  __syncthreads();
  for(int off=1; off<256; off<<=1){
    int x = (t >= off) ? sm[t-off] : 0;
    __syncthreads();
    sm[t] += x;
    __syncthreads();
  }
  if(t < nblocks) partials[t] = sm[t] - v;  // exclusive
}

__global__ __launch_bounds__(256) void k_scan3(int* __restrict__ row_ptr, const int* __restrict__ partials,
                                               int* __restrict__ cursor){
  int i = blockIdx.x*256 + threadIdx.x;
  if(i < N_NODES){
    int rp = row_ptr[i] + partials[blockIdx.x];
    row_ptr[i] = rp;
    cursor[i]  = rp;
  }
  if(i == 0) row_ptr[N_NODES] = ETOT;
}

__global__ __launch_bounds__(256) void k_scatter(const int* __restrict__ src, const int* __restrict__ dst,
                                                 int* __restrict__ cursor, int* __restrict__ src_sorted){
  int i = blockIdx.x*256 + threadIdx.x;
  if(i < ETOT){
    int d, s;
    if(i < NE){ d = dst[i]; s = src[i]; }
    else      { d = i - NE; s = i - NE; }
    int pos = atomicAdd(&cursor[d], 1);
    src_sorted[pos] = s;
  }
}

// ---------------- GEMM1: h1 = x @ W1  (50000x512 @ 512x128) ----------------

__global__ __launch_bounds__(256) void k_gemm1(const float* __restrict__ x, const float* __restrict__ W,
                                               float* __restrict__ h1){
  __shared__ float As[16][64];
  __shared__ float Bs[16][128];
  int tid = threadIdx.x;
  int bx  = blockIdx.x;
  int tx = tid & 15, ty = tid >> 4;
  float acc[4][8];
  #pragma unroll
  for(int i=0;i<4;i++)
    #pragma unroll
    for(int j=0;j<8;j++) acc[i][j]=0.f;

  int arow = tid >> 2;            // 0..63
  int akk  = (tid & 3) << 2;      // 0,4,8,12
  int grow = bx*64 + arow;
  bool arow_ok = (grow < N_NODES);

  for(int kt=0; kt<FIN; kt+=16){
    float4 av = arow_ok ? *(const float4*)(x + (size_t)grow*FIN + kt + akk)
                        : make_float4(0.f,0.f,0.f,0.f);
    As[akk+0][arow]=av.x; As[akk+1][arow]=av.y; As[akk+2][arow]=av.z; As[akk+3][arow]=av.w;

    {
      int slot = tid;           int kr = slot>>5, c4 = slot&31;
      *(float4*)&Bs[kr][c4*4] = *(const float4*)(W + (size_t)(kt+kr)*F1 + c4*4);
      slot = tid + 256;         kr = slot>>5; c4 = slot&31;
      *(float4*)&Bs[kr][c4*4] = *(const float4*)(W + (size_t)(kt+kr)*F1 + c4*4);
    }
    __syncthreads();
    #pragma unroll
    for(int kk=0;kk<16;kk++){
      float4 a  = *(const float4*)&As[kk][ty*4];
      float4 b0 = *(const float4*)&Bs[kk][tx*4];
      float4 b1 = *(const float4*)&Bs[kk][64 + tx*4];
      float aa[4] = {a.x,a.y,a.z,a.w};
      #pragma unroll
      for(int i=0;i<4;i++){
        acc[i][0] += aa[i]*b0.x; acc[i][1] += aa[i]*b0.y;
        acc[i][2] += aa[i]*b0.z; acc[i][3] += aa[i]*b0.w;
        acc[i][4] += aa[i]*b1.x; acc[i][5] += aa[i]*b1.y;
        acc[i][6] += aa[i]*b1.z; acc[i][7] += aa[i]*b1.w;
      }
    }
    __syncthreads();
  }
  #pragma unroll
  for(int i=0;i<4;i++){
    int r = bx*64 + ty*4 + i;
    if(r < N_NODES){
      float4 o0 = make_float4(acc[i][0],acc[i][1],acc[i][2],acc[i][3]);
      float4 o1 = make_float4(acc[i][4],acc[i][5],acc[i][6],acc[i][7]);
      *(float4*)(h1 + (size_t)r*F1 + tx*4)      = o0;
      *(float4*)(h1 + (size_t)r*F1 + 64 + tx*4) = o1;
    }
  }
}

// ---------------- attention scores layer 1 ----------------

__global__ __launch_bounds__(256) void k_att1(const float* __restrict__ h1, const float* __restrict__ as_w,
                                              const float* __restrict__ ad_w,
                                              float* __restrict__ a_src, float* __restrict__ a_dst){
  int id = blockIdx.x*256 + threadIdx.x;
  if(id >= N_NODES*H1) return;
  int n = id >> 3, h = id & 7;
  const float* row = h1 + (size_t)n*F1 + h*16;
  float s1=0.f, s2=0.f;
  #pragma unroll
  for(int c=0;c<16;c++){
    float v = row[c];
    s1 += v * as_w[h*16+c];
    s2 += v * ad_w[h*16+c];
  }
  a_src[id]=s1; a_dst[id]=s2;
}

// ---------------- layer-1 aggregation: online softmax + ELU(out+b1) ----------------

__global__ __launch_bounds__(256) void k_agg1(const float* __restrict__ h1, const float* __restrict__ a_src,
                                              const float* __restrict__ a_dst,
                                              const int* __restrict__ row_ptr, const int* __restrict__ src_sorted,
                                              const float* __restrict__ b1, float* __restrict__ g){
  int wave = threadIdx.x >> 6, lane = threadIdx.x & 63;
  int n = blockIdx.x*4 + wave;
  if(n >= N_NODES) return;
  int hl = lane >> 3;                 // head for channels 2*lane, 2*lane+1
  float adv = a_dst[n*H1 + hl];
  float m = -INFINITY, ssum = 0.f;
  float accx = 0.f, accy = 0.f;
  int rs = row_ptr[n], re = row_ptr[n+1];
  const float2* h12 = (const float2*)h1;
  for(int base=rs; base<re; base+=64){
    int idx = base + lane;
    int sv = (idx < re) ? src_sorted[idx] : 0;
    int cnt = min(64, re - base);
    for(int j=0;j<cnt;j++){
      int s = __shfl(sv, j);
      float e = a_src[s*H1 + hl] + adv;
      e = e > 0.f ? e : 0.2f*e;
      float nm = fmaxf(m, e);
      float sc = __expf(m - nm);
      float p  = __expf(e - nm);
      ssum = ssum*sc + p;
      m = nm;
      float2 hv = h12[(size_t)s*64 + lane];
      accx = accx*sc + p*hv.x;
      accy = accy*sc + p*hv.y;
    }
  }
  float inv = 1.f/(ssum + 1e-16f);
  int c0 = lane*2;
  float o0 = accx*inv + b1[c0];
  float o1 = accy*inv + b1[c0+1];
  o0 = o0 > 0.f ? o0 : expm1f(o0);
  o1 = o1 > 0.f ? o1 : expm1f(o1);
  float2 o = make_float2(o0,o1);
  *(float2*)(g + (size_t)n*F1 + c0) = o;
}

// ---------------- GEMM2: h2 = g @ W2  (50000x128 @ 128x40) ----------------

__global__ __launch_bounds__(256) void k_gemm2(const float* __restrict__ g, const float* __restrict__ W2,
                                               float* __restrict__ h2){
  __shared__ float Ws[128*40];
  __shared__ float Gs[32][128];
  int tid = threadIdx.x;
  for(int i=tid; i<128*40; i+=256) Ws[i] = W2[i];
  int r0 = blockIdx.x*32;
  #pragma unroll
  for(int q=0;q<4;q++){
    int slot = tid + q*256;       // 1024 float4 slots
    int r = slot>>5, c4 = slot&31;
    int gr = r0 + r;
    float4 v = (gr < N_NODES) ? *(const float4*)(g + (size_t)gr*F1 + c4*4)
                              : make_float4(0.f,0.f,0.f,0.f);
    *(float4*)&Gs[r][c4*4] = v;
  }
  __syncthreads();
  #pragma unroll
  for(int q=0;q<5;q++){
    int o = q*256 + tid;          // 1280 outputs = 32 x 40
    int r = o/40, c = o - r*40;
    if(r0 + r < N_NODES){
      float acc = 0.f;
      #pragma unroll 4
      for(int k=0;k<128;k++) acc += Gs[r][k]*Ws[k*40+c];
      h2[(size_t)(r0+r)*F2 + c] = acc;
    }
  }
}

// ---------------- attention scores layer 2 ----------------

__global__ __launch_bounds__(256) void k_att2(const float* __restrict__ h2, const float* __restrict__ as_w,
                                              const float* __restrict__ ad_w,
                                              float* __restrict__ a_src, float* __restrict__ a_dst){
  int n = blockIdx.x*256 + threadIdx.x;
  if(n >= N_NODES) return;
  float s1=0.f, s2=0.f;
  #pragma unroll
  for(int c=0;c<F2;c++){
    float v = h2[(size_t)n*F2 + c];
    s1 += v * as_w[c];
    s2 += v * ad_w[c];
  }
  a_src[n]=s1; a_dst[n]=s2;
}

// ---------------- layer-2 aggregation + bias + log_softmax ----------------

__global__ __launch_bounds__(256) void k_agg2(const float* __restrict__ h2, const float* __restrict__ a_src,
                                              const float* __restrict__ a_dst,
                                              const int* __restrict__ row_ptr, const int* __restrict__ src_sorted,
                                              const float* __restrict__ b2, float* __restrict__ out){
  int wave = threadIdx.x >> 6, lane = threadIdx.x & 63;
  int n = blockIdx.x*4 + wave;
  if(n >= N_NODES) return;
  float adv = a_dst[n];
  float m = -INFINITY, ssum = 0.f, acc = 0.f;
  int c = (lane < F2) ? lane : (F2-1);
  int rs = row_ptr[n], re = row_ptr[n+1];
  for(int base=rs; base<re; base+=64){
    int idx = base + lane;
    int sv = (idx < re) ? src_sorted[idx] : 0;
    int cnt = min(64, re - base);
    for(int j=0;j<cnt;j++){
      int s = __shfl(sv, j);
      float e = a_src[s] + adv;
      e = e > 0.f ? e : 0.2f*e;
      float nm = fmaxf(m, e);
      float sc = __expf(m - nm);
      float p  = __expf(e - nm);
      ssum = ssum*sc + p;
      m = nm;
      acc = acc*sc + p*h2[(size_t)s*F2 + c];
    }
  }
  float v = acc/(ssum + 1e-16f) + b2[c];
  // log_softmax across lanes 0..39
  float mv = (lane < F2) ? v : -INFINITY;
  #pragma unroll
  for(int off=32; off; off>>=1) mv = fmaxf(mv, __shfl_xor(mv, off));
  float ex = (lane < F2) ? __expf(v - mv) : 0.f;
  #pragma unroll
  for(int off=32; off; off>>=1) ex += __shfl_xor(ex, off);
  if(lane < F2) out[(size_t)n*F2 + lane] = v - mv - logf(ex);
}

// ---------------- launcher ----------------

extern "C" void kernel_launch(void* const* d_in, const int* in_sizes, int n_in,
                              void* d_out, int out_size, void* d_ws, size_t ws_size,
                              hipStream_t stream) {
  const float* x        = (const float*)d_in[0];
  const int*   eidx     = (const int*)d_in[1];   // [2, NE] int32
  const float* W1       = (const float*)d_in[2];
  const float* att_src1 = (const float*)d_in[3];
  const float* att_dst1 = (const float*)d_in[4];
  const float* b1       = (const float*)d_in[5];
  const float* W2       = (const float*)d_in[6];
  const float* att_src2 = (const float*)d_in[7];
  const float* att_dst2 = (const float*)d_in[8];
  const float* b2       = (const float*)d_in[9];
  float* out = (float*)d_out;

  const int* src = eidx;
  const int* dst = eidx + NE;

  // workspace layout (floats/ints)
  float* h1     = (float*)d_ws;                       // 6,400,000
  float* g      = h1 + 6400000;                       // 6,400,000
  float* h2     = g  + 6400000;                       // 2,000,000
  float* a_src1 = h2 + 2000000;                       // 400,000
  float* a_dst1 = a_src1 + 400000;                    // 400,000
  float* a_src2 = a_dst1 + 400000;                    // 50,000
  float* a_dst2 = a_src2 + 50000;                     // 50,000
  int* row_ptr  = (int*)(a_dst2 + 50000);             // 50,001 (+pad)
  int* cursor   = row_ptr + 50002;                    // 50,000 (+pad)
  int* partials = cursor + 50002;                     // 256
  int* src_sorted = partials + 256;                   // 850,000

  const int SCAN_BLOCKS = (N_NODES + 255)/256;        // 196

  // CSR build (cursor doubles as deg buffer)
  hipMemsetAsync(cursor, 0, (size_t)N_NODES*sizeof(int), stream);
  k_hist   <<<(ETOT+255)/256, 256, 0, stream>>>(dst, cursor);
  k_scan1  <<<SCAN_BLOCKS, 256, 0, stream>>>(cursor, row_ptr, partials);
  k_scan2  <<<1, 256, 0, stream>>>(partials, SCAN_BLOCKS);
  k_scan3  <<<SCAN_BLOCKS, 256, 0, stream>>>(row_ptr, partials, cursor);
  k_scatter<<<(ETOT+255)/256, 256, 0, stream>>>(src, dst, cursor, src_sorted);

  // layer 1
  k_gemm1<<<(N_NODES+63)/64, 256, 0, stream>>>(x, W1, h1);
  k_att1 <<<(N_NODES*H1+255)/256, 256, 0, stream>>>(h1, att_src1, att_dst1, a_src1, a_dst1);
  k_agg1 <<<(N_NODES+3)/4, 256, 0, stream>>>(h1, a_src1, a_dst1, row_ptr, src_sorted, b1, g);

  // layer 2
  k_gemm2<<<(N_NODES+31)/32, 256, 0, stream>>>(g, W2, h2);
  k_att2 <<<(N_NODES+255)/256, 256, 0, stream>>>(h2, att_src2, att_dst2, a_src2, a_dst2);
  k_agg2 <<<(N_NODES+3)/4, 256, 0, stream>>>(h2, a_src2, a_dst2, row_ptr, src_sorted, b2, out);
}

// Round 2
// 510.524 us; speedup vs baseline: 1.0342x; 1.0342x over previous
//
#include <hip/hip_runtime.h>
#include <math.h>

#define N_NODES 50000
#define FIN 512
#define NE 800000
#define ETOT 850000   // NE + N_NODES self loops
#define F1 128        // H1*C1
#define H1 8
#define F2 40

typedef __attribute__((ext_vector_type(8))) short bf16x8;
typedef __attribute__((ext_vector_type(4))) float f32x4;

__device__ inline ushort f2bf(float f){
  union{float f; unsigned u;} v; v.f=f;
  return (ushort)((v.u + 0x8000u) >> 16);   // round-half-up to bf16
}

// ---------------- CSR build ----------------

__global__ __launch_bounds__(256) void k_hist(const int* __restrict__ dst, int* __restrict__ deg){
  int i = blockIdx.x*256 + threadIdx.x;
  if(i < ETOT){
    int d = (i < NE) ? dst[i] : (i - NE);
    atomicAdd(&deg[d], 1);
  }
}

__global__ __launch_bounds__(256) void k_scan1(const int* __restrict__ deg, int* __restrict__ row_ptr,
                                               int* __restrict__ partials){
  __shared__ int sm[256];
  int t = threadIdx.x;
  int i = blockIdx.x*256 + t;
  int v = (i < N_NODES) ? deg[i] : 0;
  sm[t] = v;
  __syncthreads();
  for(int off=1; off<256; off<<=1){
    int x = (t >= off) ? sm[t-off] : 0;
    __syncthreads();
    sm[t] += x;
    __syncthreads();
  }
  if(i < N_NODES) row_ptr[i] = sm[t] - v;   // exclusive within block
  if(t == 255) partials[blockIdx.x] = sm[255];
}

__global__ __launch_bounds__(256) void k_scan2(int* __restrict__ partials, int nblocks){
  __shared__ int sm[256];
  int t = threadIdx.x;
  int v = (t < nblocks) ? partials[t] : 0;
  sm[t] = v;
  __syncthreads();
  for(int off=1; off<256; off<<=1){
    int x = (t >= off) ? sm[t-off] : 0;
    __syncthreads();
    sm[t] += x;
    __syncthreads();
  }
  if(t < nblocks) partials[t] = sm[t] - v;  // exclusive
}

__global__ __launch_bounds__(256) void k_scan3(int* __restrict__ row_ptr, const int* __restrict__ partials,
                                               int* __restrict__ cursor){
  int i = blockIdx.x*256 + threadIdx.x;
  if(i < N_NODES){
    int rp = row_ptr[i] + partials[blockIdx.x];
    row_ptr[i] = rp;
    cursor[i]  = rp;
  }
  if(i == 0) row_ptr[N_NODES] = ETOT;
}

__global__ __launch_bounds__(256) void k_scatter(const int* __restrict__ src, const int* __restrict__ dst,
                                                 int* __restrict__ cursor, int* __restrict__ src_sorted){
  int i = blockIdx.x*256 + threadIdx.x;
  if(i < ETOT){
    int d, s;
    if(i < NE){ d = dst[i]; s = src[i]; }
    else      { d = i - NE; s = i - NE; }
    int pos = atomicAdd(&cursor[d], 1);
    src_sorted[pos] = s;
  }
}

// ---------------- GEMM1 (bf16 MFMA): h1 = x @ W1  (50000x512 @ 512x128) ----------------
// Block: 256 thr = 4 waves (2x2). Tile 64(M) x 128(N), BK=32.
// A staged [m][k] bf16, B staged transposed [n][k] bf16, rows padded to 40.

__global__ __launch_bounds__(256) void k_gemm1(const float* __restrict__ x, const float* __restrict__ W,
                                               float* __restrict__ h1){
  __shared__ ushort Asm[64][40];
  __shared__ ushort Bsm[128][40];
  int tid  = threadIdx.x;
  int wave = tid >> 6, lane = tid & 63;
  int wq = wave >> 1, wr = wave & 1;          // wave grid 2x2 over 64x128
  int l15 = lane & 15, quad = lane >> 4;
  int bx = blockIdx.x;

  f32x4 acc[2][4];
  #pragma unroll
  for(int i=0;i<2;i++)
    #pragma unroll
    for(int j=0;j<4;j++) acc[i][j] = (f32x4){0.f,0.f,0.f,0.f};

  // A staging map: slot s (0..511): m=s>>3, k4=(s&7)*4
  int am0 = tid >> 3,        ak0 = (tid & 7) << 2;
  int am1 = (tid+256) >> 3,  ak1 = ak0;      // (s&7) identical for s and s+256? no: (tid+256)&7 == tid&7 ✓
  int agr0 = bx*64 + am0, agr1 = bx*64 + am1;
  bool aok0 = agr0 < N_NODES, aok1 = agr1 < N_NODES;

  for(int kt=0; kt<FIN; kt+=32){
    // ---- global loads (before barrier so they overlap prior compute) ----
    float4 a0 = aok0 ? *(const float4*)(x + (size_t)agr0*FIN + kt + ak0) : make_float4(0,0,0,0);
    float4 a1 = aok1 ? *(const float4*)(x + (size_t)agr1*FIN + kt + ak1) : make_float4(0,0,0,0);
    float4 bv[4];
    #pragma unroll
    for(int q=0;q<4;q++){
      int s = tid + q*256;                   // 1024 slots: kr=s>>5, n4=(s&31)*4
      int kr = s >> 5, n4 = (s & 31) << 2;
      bv[q] = *(const float4*)(W + (size_t)(kt+kr)*F1 + n4);
    }
    __syncthreads();   // protect previous iteration's frag reads
    // ---- LDS writes (converted) ----
    { ushort4 p = make_ushort4(f2bf(a0.x),f2bf(a0.y),f2bf(a0.z),f2bf(a0.w));
      *(ushort4*)&Asm[am0][ak0] = p; }
    { ushort4 p = make_ushort4(f2bf(a1.x),f2bf(a1.y),f2bf(a1.z),f2bf(a1.w));
      *(ushort4*)&Asm[am1][ak1] = p; }
    #pragma unroll
    for(int q=0;q<4;q++){
      int s = tid + q*256;
      int kr = s >> 5, n4 = (s & 31) << 2;
      Bsm[n4+0][kr] = f2bf(bv[q].x);
      Bsm[n4+1][kr] = f2bf(bv[q].y);
      Bsm[n4+2][kr] = f2bf(bv[q].z);
      Bsm[n4+3][kr] = f2bf(bv[q].w);
    }
    __syncthreads();
    // ---- fragments + MFMA ----
    bf16x8 af[2], bf[4];
    #pragma unroll
    for(int tm=0;tm<2;tm++){
      int m = wq*32 + tm*16 + l15;
      af[tm] = *(bf16x8*)&Asm[m][quad*8];
    }
    #pragma unroll
    for(int tn=0;tn<4;tn++){
      int n = wr*64 + tn*16 + l15;
      bf[tn] = *(bf16x8*)&Bsm[n][quad*8];
    }
    #pragma unroll
    for(int tm=0;tm<2;tm++)
      #pragma unroll
      for(int tn=0;tn<4;tn++)
        acc[tm][tn] = __builtin_amdgcn_mfma_f32_16x16x32_bf16(af[tm], bf[tn], acc[tm][tn], 0,0,0);
  }

  // ---- epilogue: D row = quad*4 + r, col = lane&15 ----
  #pragma unroll
  for(int tm=0;tm<2;tm++){
    #pragma unroll
    for(int r=0;r<4;r++){
      int row = bx*64 + wq*32 + tm*16 + quad*4 + r;
      if(row < N_NODES){
        #pragma unroll
        for(int tn=0;tn<4;tn++){
          int col = wr*64 + tn*16 + l15;
          h1[(size_t)row*F1 + col] = acc[tm][tn][r];
        }
      }
    }
  }
}

// ---------------- attention scores layer 1 ----------------

__global__ __launch_bounds__(256) void k_att1(const float* __restrict__ h1, const float* __restrict__ as_w,
                                              const float* __restrict__ ad_w,
                                              float* __restrict__ a_src, float* __restrict__ a_dst){
  int id = blockIdx.x*256 + threadIdx.x;
  if(id >= N_NODES*H1) return;
  int n = id >> 3, h = id & 7;
  const float* row = h1 + (size_t)n*F1 + h*16;
  float s1=0.f, s2=0.f;
  #pragma unroll
  for(int c=0;c<16;c++){
    float v = row[c];
    s1 += v * as_w[h*16+c];
    s2 += v * ad_w[h*16+c];
  }
  a_src[id]=s1; a_dst[id]=s2;
}

// ---------------- layer-1 aggregation: online softmax + ELU(out+b1) ----------------

__global__ __launch_bounds__(256) void k_agg1(const float* __restrict__ h1, const float* __restrict__ a_src,
                                              const float* __restrict__ a_dst,
                                              const int* __restrict__ row_ptr, const int* __restrict__ src_sorted,
                                              const float* __restrict__ b1, float* __restrict__ g){
  int wave = threadIdx.x >> 6, lane = threadIdx.x & 63;
  int n = blockIdx.x*4 + wave;
  if(n >= N_NODES) return;
  int hl = lane >> 3;                 // head for channels 2*lane, 2*lane+1
  float adv = a_dst[n*H1 + hl];
  float m = -INFINITY, ssum = 0.f;
  float accx = 0.f, accy = 0.f;
  int rs = row_ptr[n], re = row_ptr[n+1];
  const float2* h12 = (const float2*)h1;
  for(int base=rs; base<re; base+=64){
    int idx = base + lane;
    int sv = (idx < re) ? src_sorted[idx] : 0;
    int cnt = min(64, re - base);
    for(int j=0;j<cnt;j++){
      int s = __shfl(sv, j);
      float e = a_src[s*H1 + hl] + adv;
      e = e > 0.f ? e : 0.2f*e;
      float nm = fmaxf(m, e);
      float sc = __expf(m - nm);
      float p  = __expf(e - nm);
      ssum = ssum*sc + p;
      m = nm;
      float2 hv = h12[(size_t)s*64 + lane];
      accx = accx*sc + p*hv.x;
      accy = accy*sc + p*hv.y;
    }
  }
  float inv = 1.f/(ssum + 1e-16f);
  int c0 = lane*2;
  float o0 = accx*inv + b1[c0];
  float o1 = accy*inv + b1[c0+1];
  o0 = o0 > 0.f ? o0 : expm1f(o0);
  o1 = o1 > 0.f ? o1 : expm1f(o1);
  float2 o = make_float2(o0,o1);
  *(float2*)(g + (size_t)n*F1 + c0) = o;
}

// ---------------- GEMM2: h2 = g @ W2  (50000x128 @ 128x40) ----------------

__global__ __launch_bounds__(256) void k_gemm2(const float* __restrict__ g, const float* __restrict__ W2,
                                               float* __restrict__ h2){
  __shared__ float Ws[128*40];
  __shared__ float Gs[32][128];
  int tid = threadIdx.x;
  for(int i=tid; i<128*40; i+=256) Ws[i] = W2[i];
  int r0 = blockIdx.x*32;
  #pragma unroll
  for(int q=0;q<4;q++){
    int slot = tid + q*256;       // 1024 float4 slots
    int r = slot>>5, c4 = slot&31;
    int gr = r0 + r;
    float4 v = (gr < N_NODES) ? *(const float4*)(g + (size_t)gr*F1 + c4*4)
                              : make_float4(0.f,0.f,0.f,0.f);
    *(float4*)&Gs[r][c4*4] = v;
  }
  __syncthreads();
  #pragma unroll
  for(int q=0;q<5;q++){
    int o = q*256 + tid;          // 1280 outputs = 32 x 40
    int r = o/40, c = o - r*40;
    if(r0 + r < N_NODES){
      float acc = 0.f;
      #pragma unroll 4
      for(int k=0;k<128;k++) acc += Gs[r][k]*Ws[k*40+c];
      h2[(size_t)(r0+r)*F2 + c] = acc;
    }
  }
}

// ---------------- attention scores layer 2 ----------------

__global__ __launch_bounds__(256) void k_att2(const float* __restrict__ h2, const float* __restrict__ as_w,
                                              const float* __restrict__ ad_w,
                                              float* __restrict__ a_src, float* __restrict__ a_dst){
  int n = blockIdx.x*256 + threadIdx.x;
  if(n >= N_NODES) return;
  float s1=0.f, s2=0.f;
  #pragma unroll
  for(int c=0;c<F2;c++){
    float v = h2[(size_t)n*F2 + c];
    s1 += v * as_w[c];
    s2 += v * ad_w[c];
  }
  a_src[n]=s1; a_dst[n]=s2;
}

// ---------------- layer-2 aggregation + bias + log_softmax ----------------

__global__ __launch_bounds__(256) void k_agg2(const float* __restrict__ h2, const float* __restrict__ a_src,
                                              const float* __restrict__ a_dst,
                                              const int* __restrict__ row_ptr, const int* __restrict__ src_sorted,
                                              const float* __restrict__ b2, float* __restrict__ out){
  int wave = threadIdx.x >> 6, lane = threadIdx.x & 63;
  int n = blockIdx.x*4 + wave;
  if(n >= N_NODES) return;
  float adv = a_dst[n];
  float m = -INFINITY, ssum = 0.f, acc = 0.f;
  int c = (lane < F2) ? lane : (F2-1);
  int rs = row_ptr[n], re = row_ptr[n+1];
  for(int base=rs; base<re; base+=64){
    int idx = base + lane;
    int sv = (idx < re) ? src_sorted[idx] : 0;
    int cnt = min(64, re - base);
    for(int j=0;j<cnt;j++){
      int s = __shfl(sv, j);
      float e = a_src[s] + adv;
      e = e > 0.f ? e : 0.2f*e;
      float nm = fmaxf(m, e);
      float sc = __expf(m - nm);
      float p  = __expf(e - nm);
      ssum = ssum*sc + p;
      m = nm;
      acc = acc*sc + p*h2[(size_t)s*F2 + c];
    }
  }
  float v = acc/(ssum + 1e-16f) + b2[c];
  // log_softmax across lanes 0..39
  float mv = (lane < F2) ? v : -INFINITY;
  #pragma unroll
  for(int off=32; off; off>>=1) mv = fmaxf(mv, __shfl_xor(mv, off));
  float ex = (lane < F2) ? __expf(v - mv) : 0.f;
  #pragma unroll
  for(int off=32; off; off>>=1) ex += __shfl_xor(ex, off);
  if(lane < F2) out[(size_t)n*F2 + lane] = v - mv - logf(ex);
}

// ---------------- launcher ----------------

extern "C" void kernel_launch(void* const* d_in, const int* in_sizes, int n_in,
                              void* d_out, int out_size, void* d_ws, size_t ws_size,
                              hipStream_t stream) {
  const float* x        = (const float*)d_in[0];
  const int*   eidx     = (const int*)d_in[1];   // [2, NE] int32
  const float* W1       = (const float*)d_in[2];
  const float* att_src1 = (const float*)d_in[3];
  const float* att_dst1 = (const float*)d_in[4];
  const float* b1       = (const float*)d_in[5];
  const float* W2       = (const float*)d_in[6];
  const float* att_src2 = (const float*)d_in[7];
  const float* att_dst2 = (const float*)d_in[8];
  const float* b2       = (const float*)d_in[9];
  float* out = (float*)d_out;

  const int* src = eidx;
  const int* dst = eidx + NE;

  // workspace layout (floats/ints)
  float* h1     = (float*)d_ws;                       // 6,400,000
  float* g      = h1 + 6400000;                       // 6,400,000
  float* h2     = g  + 6400000;                       // 2,000,000
  float* a_src1 = h2 + 2000000;                       // 400,000
  float* a_dst1 = a_src1 + 400000;                    // 400,000
  float* a_src2 = a_dst1 + 400000;                    // 50,000
  float* a_dst2 = a_src2 + 50000;                     // 50,000
  int* row_ptr  = (int*)(a_dst2 + 50000);             // 50,001 (+pad)
  int* cursor   = row_ptr + 50002;                    // 50,000 (+pad)
  int* partials = cursor + 50002;                     // 256
  int* src_sorted = partials + 256;                   // 850,000

  const int SCAN_BLOCKS = (N_NODES + 255)/256;        // 196

  // CSR build (cursor doubles as deg buffer)
  hipMemsetAsync(cursor, 0, (size_t)N_NODES*sizeof(int), stream);
  k_hist   <<<(ETOT+255)/256, 256, 0, stream>>>(dst, cursor);
  k_scan1  <<<SCAN_BLOCKS, 256, 0, stream>>>(cursor, row_ptr, partials);
  k_scan2  <<<1, 256, 0, stream>>>(partials, SCAN_BLOCKS);
  k_scan3  <<<SCAN_BLOCKS, 256, 0, stream>>>(row_ptr, partials, cursor);
  k_scatter<<<(ETOT+255)/256, 256, 0, stream>>>(src, dst, cursor, src_sorted);

  // layer 1
  k_gemm1<<<(N_NODES+63)/64, 256, 0, stream>>>(x, W1, h1);
  k_att1 <<<(N_NODES*H1+255)/256, 256, 0, stream>>>(h1, att_src1, att_dst1, a_src1, a_dst1);
  k_agg1 <<<(N_NODES+3)/4, 256, 0, stream>>>(h1, a_src1, a_dst1, row_ptr, src_sorted, b1, g);

  // layer 2
  k_gemm2<<<(N_NODES+31)/32, 256, 0, stream>>>(g, W2, h2);
  k_att2 <<<(N_NODES+255)/256, 256, 0, stream>>>(h2, att_src2, att_dst2, a_src2, a_dst2);
  k_agg2 <<<(N_NODES+3)/4, 256, 0, stream>>>(h2, a_src2, a_dst2, row_ptr, src_sorted, b2, out);
}

// Round 3
// 497.897 us; speedup vs baseline: 1.0605x; 1.0254x over previous
//
#include <hip/hip_runtime.h>
#include <math.h>

#define N_NODES 50000
#define FIN 512
#define NE 800000
#define ETOT 850000   // NE + N_NODES self loops
#define F1 128        // H1*C1
#define H1 8
#define F2 40

typedef __attribute__((ext_vector_type(8))) short bf16x8;
typedef __attribute__((ext_vector_type(8))) ushort u16x8;
typedef __attribute__((ext_vector_type(4))) float f32x4;

__device__ inline ushort f2bf(float f){
  union{float f; unsigned u;} v; v.f=f;
  return (ushort)((v.u + 0x8000u) >> 16);   // round-to-nearest-ish bf16
}

// ---------------- CSR build ----------------

__global__ __launch_bounds__(256) void k_hist(const int* __restrict__ dst, int* __restrict__ deg){
  int i = blockIdx.x*256 + threadIdx.x;
  if(i < ETOT){
    int d = (i < NE) ? dst[i] : (i - NE);
    atomicAdd(&deg[d], 1);
  }
}

__global__ __launch_bounds__(256) void k_scan1(const int* __restrict__ deg, int* __restrict__ row_ptr,
                                               int* __restrict__ partials){
  __shared__ int sm[256];
  int t = threadIdx.x;
  int i = blockIdx.x*256 + t;
  int v = (i < N_NODES) ? deg[i] : 0;
  sm[t] = v;
  __syncthreads();
  for(int off=1; off<256; off<<=1){
    int x = (t >= off) ? sm[t-off] : 0;
    __syncthreads();
    sm[t] += x;
    __syncthreads();
  }
  if(i < N_NODES) row_ptr[i] = sm[t] - v;   // exclusive within block
  if(t == 255) partials[blockIdx.x] = sm[255];
}

__global__ __launch_bounds__(256) void k_scan2(int* __restrict__ partials, int nblocks){
  __shared__ int sm[256];
  int t = threadIdx.x;
  int v = (t < nblocks) ? partials[t] : 0;
  sm[t] = v;
  __syncthreads();
  for(int off=1; off<256; off<<=1){
    int x = (t >= off) ? sm[t-off] : 0;
    __syncthreads();
    sm[t] += x;
    __syncthreads();
  }
  if(t < nblocks) partials[t] = sm[t] - v;  // exclusive
}

__global__ __launch_bounds__(256) void k_scan3(int* __restrict__ row_ptr, const int* __restrict__ partials,
                                               int* __restrict__ cursor){
  int i = blockIdx.x*256 + threadIdx.x;
  if(i < N_NODES){
    int rp = row_ptr[i] + partials[blockIdx.x];
    row_ptr[i] = rp;
    cursor[i]  = rp;
  }
  if(i == 0) row_ptr[N_NODES] = ETOT;
}

__global__ __launch_bounds__(256) void k_scatter(const int* __restrict__ src, const int* __restrict__ dst,
                                                 int* __restrict__ cursor, int* __restrict__ src_sorted){
  int i = blockIdx.x*256 + threadIdx.x;
  if(i < ETOT){
    int d, s;
    if(i < NE){ d = dst[i]; s = src[i]; }
    else      { d = i - NE; s = i - NE; }
    int pos = atomicAdd(&cursor[d], 1);
    src_sorted[pos] = s;
  }
}

// ---------------- W1 transpose+convert: Wt[n][k] = bf16(W[k][n]) ----------------

__global__ __launch_bounds__(256) void k_cvtW(const float* __restrict__ W, ushort* __restrict__ Wt){
  int id = blockIdx.x*256 + threadIdx.x;    // 65536
  int k = id >> 7, n = id & 127;
  Wt[(size_t)n*FIN + k] = f2bf(W[id]);
}

// ---------------- GEMM1 (bf16 MFMA): h1 = x @ W1  (50000x512 @ 512x128) ----------------
// Block: 256 thr = 4 waves (2x2 over 64x128). BK=32.
// A: double-buffered LDS [64][40] bf16 (conflict-free 16B stores/reads).
// B: fragments loaded directly from global Wt (L2-resident, no LDS, no transpose).

__global__ __launch_bounds__(256) void k_gemm1(const float* __restrict__ x, const ushort* __restrict__ Wt,
                                               float* __restrict__ h1){
  __shared__ ushort Asm[2][64][40];
  int tid  = threadIdx.x;
  int wave = tid >> 6, lane = tid & 63;
  int wq = wave >> 1, wr = wave & 1;
  int l15 = lane & 15, quad = lane >> 4;
  int bx = blockIdx.x;

  f32x4 acc[2][4];
  #pragma unroll
  for(int i=0;i<2;i++)
    #pragma unroll
    for(int j=0;j<4;j++) acc[i][j] = (f32x4){0.f,0.f,0.f,0.f};

  // A staging: one 16B LDS write per thread per tile. m = tid>>2, k8 = (tid&3)*8
  int am  = tid >> 2;
  int ak8 = (tid & 3) << 3;
  int agr = bx*64 + am;
  bool aok = agr < N_NODES;
  const float* xrow = x + (size_t)agr*FIN + ak8;

  // prologue: stage tile kt=0 into buf 0
  {
    float4 a0 = aok ? *(const float4*)(xrow + 0) : make_float4(0,0,0,0);
    float4 a1 = aok ? *(const float4*)(xrow + 4) : make_float4(0,0,0,0);
    u16x8 p = { f2bf(a0.x),f2bf(a0.y),f2bf(a0.z),f2bf(a0.w),
                f2bf(a1.x),f2bf(a1.y),f2bf(a1.z),f2bf(a1.w) };
    *(u16x8*)&Asm[0][am][ak8] = p;
  }
  __syncthreads();

  const ushort* wtb[4];
  #pragma unroll
  for(int tn=0;tn<4;tn++)
    wtb[tn] = Wt + (size_t)(wr*64 + tn*16 + l15)*FIN + quad*8;

  for(int kt=0; kt<FIN; kt+=32){
    int cur = (kt >> 5) & 1;
    bool have_next = (kt + 32) < FIN;

    // prefetch next A tile (global)
    float4 n0 = make_float4(0,0,0,0), n1 = make_float4(0,0,0,0);
    if(have_next && aok){
      n0 = *(const float4*)(xrow + kt + 32);
      n1 = *(const float4*)(xrow + kt + 36);
    }

    // B fragments direct from global Wt (L2-resident)
    bf16x8 bfr[4];
    #pragma unroll
    for(int tn=0;tn<4;tn++)
      bfr[tn] = *(const bf16x8*)(wtb[tn] + kt);

    // A fragments from LDS
    bf16x8 af[2];
    #pragma unroll
    for(int tm=0;tm<2;tm++)
      af[tm] = *(bf16x8*)&Asm[cur][wq*32 + tm*16 + l15][quad*8];

    #pragma unroll
    for(int tm=0;tm<2;tm++)
      #pragma unroll
      for(int tn=0;tn<4;tn++)
        acc[tm][tn] = __builtin_amdgcn_mfma_f32_16x16x32_bf16(af[tm], bfr[tn], acc[tm][tn], 0,0,0);

    // stage next tile into the other buffer
    if(have_next){
      u16x8 p = { f2bf(n0.x),f2bf(n0.y),f2bf(n0.z),f2bf(n0.w),
                  f2bf(n1.x),f2bf(n1.y),f2bf(n1.z),f2bf(n1.w) };
      *(u16x8*)&Asm[cur^1][am][ak8] = p;
    }
    __syncthreads();
  }

  // epilogue: D row = quad*4 + r, col = lane&15
  #pragma unroll
  for(int tm=0;tm<2;tm++){
    #pragma unroll
    for(int r=0;r<4;r++){
      int row = bx*64 + wq*32 + tm*16 + quad*4 + r;
      if(row < N_NODES){
        #pragma unroll
        for(int tn=0;tn<4;tn++){
          int col = wr*64 + tn*16 + l15;
          h1[(size_t)row*F1 + col] = acc[tm][tn][r];
        }
      }
    }
  }
}

// ---------------- attention scores layer 1 ----------------

__global__ __launch_bounds__(256) void k_att1(const float* __restrict__ h1, const float* __restrict__ as_w,
                                              const float* __restrict__ ad_w,
                                              float* __restrict__ a_src, float* __restrict__ a_dst){
  int id = blockIdx.x*256 + threadIdx.x;
  if(id >= N_NODES*H1) return;
  int n = id >> 3, h = id & 7;
  const float* row = h1 + (size_t)n*F1 + h*16;
  float s1=0.f, s2=0.f;
  #pragma unroll
  for(int c=0;c<16;c++){
    float v = row[c];
    s1 += v * as_w[h*16+c];
    s2 += v * ad_w[h*16+c];
  }
  a_src[id]=s1; a_dst[id]=s2;
}

// ---------------- layer-1 aggregation: online softmax + ELU(out+b1) ----------------

__global__ __launch_bounds__(256) void k_agg1(const float* __restrict__ h1, const float* __restrict__ a_src,
                                              const float* __restrict__ a_dst,
                                              const int* __restrict__ row_ptr, const int* __restrict__ src_sorted,
                                              const float* __restrict__ b1, float* __restrict__ g){
  int wave = threadIdx.x >> 6, lane = threadIdx.x & 63;
  int n = blockIdx.x*4 + wave;
  if(n >= N_NODES) return;
  int hl = lane >> 3;                 // head for channels 2*lane, 2*lane+1
  float adv = a_dst[n*H1 + hl];
  float m = -INFINITY, ssum = 0.f;
  float accx = 0.f, accy = 0.f;
  int rs = row_ptr[n], re = row_ptr[n+1];
  const float2* h12 = (const float2*)h1;
  for(int base=rs; base<re; base+=64){
    int idx = base + lane;
    int sv = (idx < re) ? src_sorted[idx] : 0;
    int cnt = min(64, re - base);
    for(int j=0;j<cnt;j++){
      int s = __shfl(sv, j);
      float e = a_src[s*H1 + hl] + adv;
      e = e > 0.f ? e : 0.2f*e;
      float nm = fmaxf(m, e);
      float sc = __expf(m - nm);
      float p  = __expf(e - nm);
      ssum = ssum*sc + p;
      m = nm;
      float2 hv = h12[(size_t)s*64 + lane];
      accx = accx*sc + p*hv.x;
      accy = accy*sc + p*hv.y;
    }
  }
  float inv = 1.f/(ssum + 1e-16f);
  int c0 = lane*2;
  float o0 = accx*inv + b1[c0];
  float o1 = accy*inv + b1[c0+1];
  o0 = o0 > 0.f ? o0 : expm1f(o0);
  o1 = o1 > 0.f ? o1 : expm1f(o1);
  float2 o = make_float2(o0,o1);
  *(float2*)(g + (size_t)n*F1 + c0) = o;
}

// ---------------- GEMM2: h2 = g @ W2  (50000x128 @ 128x40) ----------------

__global__ __launch_bounds__(256) void k_gemm2(const float* __restrict__ g, const float* __restrict__ W2,
                                               float* __restrict__ h2){
  __shared__ float Ws[128*40];
  __shared__ float Gs[32][128];
  int tid = threadIdx.x;
  for(int i=tid; i<128*40; i+=256) Ws[i] = W2[i];
  int r0 = blockIdx.x*32;
  #pragma unroll
  for(int q=0;q<4;q++){
    int slot = tid + q*256;       // 1024 float4 slots
    int r = slot>>5, c4 = slot&31;
    int gr = r0 + r;
    float4 v = (gr < N_NODES) ? *(const float4*)(g + (size_t)gr*F1 + c4*4)
                              : make_float4(0.f,0.f,0.f,0.f);
    *(float4*)&Gs[r][c4*4] = v;
  }
  __syncthreads();
  #pragma unroll
  for(int q=0;q<5;q++){
    int o = q*256 + tid;          // 1280 outputs = 32 x 40
    int r = o/40, c = o - r*40;
    if(r0 + r < N_NODES){
      float acc = 0.f;
      #pragma unroll 4
      for(int k=0;k<128;k++) acc += Gs[r][k]*Ws[k*40+c];
      h2[(size_t)(r0+r)*F2 + c] = acc;
    }
  }
}

// ---------------- attention scores layer 2 ----------------

__global__ __launch_bounds__(256) void k_att2(const float* __restrict__ h2, const float* __restrict__ as_w,
                                              const float* __restrict__ ad_w,
                                              float* __restrict__ a_src, float* __restrict__ a_dst){
  int n = blockIdx.x*256 + threadIdx.x;
  if(n >= N_NODES) return;
  float s1=0.f, s2=0.f;
  #pragma unroll
  for(int c=0;c<F2;c++){
    float v = h2[(size_t)n*F2 + c];
    s1 += v * as_w[c];
    s2 += v * ad_w[c];
  }
  a_src[n]=s1; a_dst[n]=s2;
}

// ---------------- layer-2 aggregation + bias + log_softmax ----------------

__global__ __launch_bounds__(256) void k_agg2(const float* __restrict__ h2, const float* __restrict__ a_src,
                                              const float* __restrict__ a_dst,
                                              const int* __restrict__ row_ptr, const int* __restrict__ src_sorted,
                                              const float* __restrict__ b2, float* __restrict__ out){
  int wave = threadIdx.x >> 6, lane = threadIdx.x & 63;
  int n = blockIdx.x*4 + wave;
  if(n >= N_NODES) return;
  float adv = a_dst[n];
  float m = -INFINITY, ssum = 0.f, acc = 0.f;
  int c = (lane < F2) ? lane : (F2-1);
  int rs = row_ptr[n], re = row_ptr[n+1];
  for(int base=rs; base<re; base+=64){
    int idx = base + lane;
    int sv = (idx < re) ? src_sorted[idx] : 0;
    int cnt = min(64, re - base);
    for(int j=0;j<cnt;j++){
      int s = __shfl(sv, j);
      float e = a_src[s] + adv;
      e = e > 0.f ? e : 0.2f*e;
      float nm = fmaxf(m, e);
      float sc = __expf(m - nm);
      float p  = __expf(e - nm);
      ssum = ssum*sc + p;
      m = nm;
      acc = acc*sc + p*h2[(size_t)s*F2 + c];
    }
  }
  float v = acc/(ssum + 1e-16f) + b2[c];
  // log_softmax across lanes 0..39
  float mv = (lane < F2) ? v : -INFINITY;
  #pragma unroll
  for(int off=32; off; off>>=1) mv = fmaxf(mv, __shfl_xor(mv, off));
  float ex = (lane < F2) ? __expf(v - mv) : 0.f;
  #pragma unroll
  for(int off=32; off; off>>=1) ex += __shfl_xor(ex, off);
  if(lane < F2) out[(size_t)n*F2 + lane] = v - mv - logf(ex);
}

// ---------------- launcher ----------------

extern "C" void kernel_launch(void* const* d_in, const int* in_sizes, int n_in,
                              void* d_out, int out_size, void* d_ws, size_t ws_size,
                              hipStream_t stream) {
  const float* x        = (const float*)d_in[0];
  const int*   eidx     = (const int*)d_in[1];   // [2, NE] int32
  const float* W1       = (const float*)d_in[2];
  const float* att_src1 = (const float*)d_in[3];
  const float* att_dst1 = (const float*)d_in[4];
  const float* b1       = (const float*)d_in[5];
  const float* W2       = (const float*)d_in[6];
  const float* att_src2 = (const float*)d_in[7];
  const float* att_dst2 = (const float*)d_in[8];
  const float* b2       = (const float*)d_in[9];
  float* out = (float*)d_out;

  const int* src = eidx;
  const int* dst = eidx + NE;

  // workspace layout (floats/ints)
  float* h1     = (float*)d_ws;                       // 6,400,000
  float* g      = h1 + 6400000;                       // 6,400,000
  float* h2     = g  + 6400000;                       // 2,000,000
  float* a_src1 = h2 + 2000000;                       // 400,000
  float* a_dst1 = a_src1 + 400000;                    // 400,000
  float* a_src2 = a_dst1 + 400000;                    // 50,000
  float* a_dst2 = a_src2 + 50000;                     // 50,000
  int* row_ptr  = (int*)(a_dst2 + 50000);             // 50,001 (+pad)
  int* cursor   = row_ptr + 50002;                    // 50,000 (+pad)
  int* partials = cursor + 50002;                     // 256
  int* src_sorted = partials + 256;                   // 850,000
  ushort* Wt    = (ushort*)(src_sorted + 850000);     // 65,536 bf16

  const int SCAN_BLOCKS = (N_NODES + 255)/256;        // 196

  // CSR build (cursor doubles as deg buffer)
  hipMemsetAsync(cursor, 0, (size_t)N_NODES*sizeof(int), stream);
  k_hist   <<<(ETOT+255)/256, 256, 0, stream>>>(dst, cursor);
  k_scan1  <<<SCAN_BLOCKS, 256, 0, stream>>>(cursor, row_ptr, partials);
  k_scan2  <<<1, 256, 0, stream>>>(partials, SCAN_BLOCKS);
  k_scan3  <<<SCAN_BLOCKS, 256, 0, stream>>>(row_ptr, partials, cursor);
  k_scatter<<<(ETOT+255)/256, 256, 0, stream>>>(src, dst, cursor, src_sorted);

  // layer 1
  k_cvtW <<<(FIN*F1+255)/256, 256, 0, stream>>>(W1, Wt);
  k_gemm1<<<(N_NODES+63)/64, 256, 0, stream>>>(x, Wt, h1);
  k_att1 <<<(N_NODES*H1+255)/256, 256, 0, stream>>>(h1, att_src1, att_dst1, a_src1, a_dst1);
  k_agg1 <<<(N_NODES+3)/4, 256, 0, stream>>>(h1, a_src1, a_dst1, row_ptr, src_sorted, b1, g);

  // layer 2
  k_gemm2<<<(N_NODES+31)/32, 256, 0, stream>>>(g, W2, h2);
  k_att2 <<<(N_NODES+255)/256, 256, 0, stream>>>(h2, att_src2, att_dst2, a_src2, a_dst2);
  k_agg2 <<<(N_NODES+3)/4, 256, 0, stream>>>(h2, a_src2, a_dst2, row_ptr, src_sorted, b2, out);
}

// Round 4
// 481.021 us; speedup vs baseline: 1.0977x; 1.0351x over previous
//
#include <hip/hip_runtime.h>
#include <math.h>

#define N_NODES 50000
#define FIN 512
#define NE 800000
#define ETOT 850000   // NE + N_NODES self loops
#define F1 128        // H1*C1
#define H1 8
#define F2 40

typedef __attribute__((ext_vector_type(8))) short bf16x8;
typedef __attribute__((ext_vector_type(8))) ushort u16x8;
typedef __attribute__((ext_vector_type(4))) float f32x4;

__device__ inline ushort f2bf(float f){
  union{float f; unsigned u;} v; v.f=f;
  return (ushort)((v.u + 0x8000u) >> 16);
}

// ---------------- CSR build ----------------

__global__ __launch_bounds__(256) void k_hist(const int* __restrict__ dst, int* __restrict__ deg){
  int i = blockIdx.x*256 + threadIdx.x;
  if(i < ETOT){
    int d = (i < NE) ? dst[i] : (i - NE);
    atomicAdd(&deg[d], 1);
  }
}

__global__ __launch_bounds__(256) void k_scan1(const int* __restrict__ deg, int* __restrict__ row_ptr,
                                               int* __restrict__ partials){
  __shared__ int sm[256];
  int t = threadIdx.x;
  int i = blockIdx.x*256 + t;
  int v = (i < N_NODES) ? deg[i] : 0;
  sm[t] = v;
  __syncthreads();
  for(int off=1; off<256; off<<=1){
    int x = (t >= off) ? sm[t-off] : 0;
    __syncthreads();
    sm[t] += x;
    __syncthreads();
  }
  if(i < N_NODES) row_ptr[i] = sm[t] - v;
  if(t == 255) partials[blockIdx.x] = sm[255];
}

__global__ __launch_bounds__(256) void k_scan2(int* __restrict__ partials, int nblocks){
  __shared__ int sm[256];
  int t = threadIdx.x;
  int v = (t < nblocks) ? partials[t] : 0;
  sm[t] = v;
  __syncthreads();
  for(int off=1; off<256; off<<=1){
    int x = (t >= off) ? sm[t-off] : 0;
    __syncthreads();
    sm[t] += x;
    __syncthreads();
  }
  if(t < nblocks) partials[t] = sm[t] - v;
}

__global__ __launch_bounds__(256) void k_scan3(int* __restrict__ row_ptr, const int* __restrict__ partials,
                                               int* __restrict__ cursor){
  int i = blockIdx.x*256 + threadIdx.x;
  if(i < N_NODES){
    int rp = row_ptr[i] + partials[blockIdx.x];
    row_ptr[i] = rp;
    cursor[i]  = rp;
  }
  if(i == 0) row_ptr[N_NODES] = ETOT;
}

__global__ __launch_bounds__(256) void k_scatter(const int* __restrict__ src, const int* __restrict__ dst,
                                                 int* __restrict__ cursor,
                                                 int* __restrict__ src_sorted, int* __restrict__ dst_sorted){
  int i = blockIdx.x*256 + threadIdx.x;
  if(i < ETOT){
    int d, s;
    if(i < NE){ d = dst[i]; s = src[i]; }
    else      { d = i - NE; s = i - NE; }
    int pos = atomicAdd(&cursor[d], 1);
    src_sorted[pos] = s;
    dst_sorted[pos] = d;
  }
}

// ---------------- W1 convert to frag-blocked layout ----------------
// Wtb[(k>>3)*1024 + n*8 + (k&7)] = bf16(W[k][n]); frag load = 16B contiguous per lane.

__global__ __launch_bounds__(256) void k_cvtW(const float* __restrict__ W, ushort* __restrict__ Wtb){
  int id = blockIdx.x*256 + threadIdx.x;    // 65536
  int k = id >> 7, n = id & 127;
  Wtb[(size_t)(k>>3)*1024 + n*8 + (k&7)] = f2bf(W[id]);
}

// ---------------- GEMM1 (bf16 MFMA): h1 = x @ W1  (50000x512 @ 512x128) ----------------
// Tile 32(M) x 128(N), BK=32, 4 waves (each wave 32 N-cols). Grid 1563 (~6 blocks/CU).
// A: double-buffered LDS. B: software-pipelined direct-global frags (L2-resident Wtb).

__global__ __launch_bounds__(256) void k_gemm1(const float* __restrict__ x, const ushort* __restrict__ Wtb,
                                               float* __restrict__ h1){
  __shared__ ushort Asm[2][32][40];
  int tid  = threadIdx.x;
  int wave = tid >> 6, lane = tid & 63;
  int l15 = lane & 15, quad = lane >> 4;
  int bx = blockIdx.x;

  f32x4 acc[2][2];
  #pragma unroll
  for(int i=0;i<2;i++)
    #pragma unroll
    for(int j=0;j<2;j++) acc[i][j] = (f32x4){0.f,0.f,0.f,0.f};

  // A staging: 256 thr cover 32 rows x 32 k (float4 each)
  int am  = tid >> 3;
  int ak4 = (tid & 7) << 2;
  int agr = bx*32 + am;
  bool aok = agr < N_NODES;
  const float* xrow = x + (size_t)agr*FIN + ak4;

  // stage kt=0
  {
    float4 a0 = aok ? *(const float4*)xrow : make_float4(0,0,0,0);
    ushort4 p = make_ushort4(f2bf(a0.x),f2bf(a0.y),f2bf(a0.z),f2bf(a0.w));
    *(ushort4*)&Asm[0][am][ak4] = p;
  }

  const ushort* wp[2];
  #pragma unroll
  for(int tn=0;tn<2;tn++)
    wp[tn] = Wtb + (size_t)quad*1024 + (size_t)(wave*32 + tn*16 + l15)*8;

  bf16x8 bcur[2];
  bcur[0] = *(const bf16x8*)wp[0];
  bcur[1] = *(const bf16x8*)wp[1];
  __syncthreads();

  for(int kt=0; kt<FIN; kt+=32){
    int cur = (kt >> 5) & 1;
    bool hn = (kt + 32) < FIN;

    float4 an = make_float4(0,0,0,0);
    if(hn && aok) an = *(const float4*)(xrow + kt + 32);

    bf16x8 bnext[2];
    if(hn){
      bnext[0] = *(const bf16x8*)(wp[0] + (size_t)(kt+32)*128);
      bnext[1] = *(const bf16x8*)(wp[1] + (size_t)(kt+32)*128);
    }

    bf16x8 af[2];
    af[0] = *(bf16x8*)&Asm[cur][l15][quad*8];
    af[1] = *(bf16x8*)&Asm[cur][16+l15][quad*8];

    #pragma unroll
    for(int tm=0;tm<2;tm++)
      #pragma unroll
      for(int tn=0;tn<2;tn++)
        acc[tm][tn] = __builtin_amdgcn_mfma_f32_16x16x32_bf16(af[tm], bcur[tn], acc[tm][tn], 0,0,0);

    if(hn){
      ushort4 p = make_ushort4(f2bf(an.x),f2bf(an.y),f2bf(an.z),f2bf(an.w));
      *(ushort4*)&Asm[cur^1][am][ak4] = p;
    }
    __syncthreads();
    bcur[0] = bnext[0];
    bcur[1] = bnext[1];
  }

  #pragma unroll
  for(int tm=0;tm<2;tm++){
    #pragma unroll
    for(int r=0;r<4;r++){
      int row = bx*32 + tm*16 + quad*4 + r;
      if(row < N_NODES){
        #pragma unroll
        for(int tn=0;tn<2;tn++){
          int col = wave*32 + tn*16 + l15;
          h1[(size_t)row*F1 + col] = acc[tm][tn][r];
        }
      }
    }
  }
}

// ---------------- attention scores layer 1 ----------------

__global__ __launch_bounds__(256) void k_att1(const float* __restrict__ h1, const float* __restrict__ as_w,
                                              const float* __restrict__ ad_w,
                                              float* __restrict__ a_src, float* __restrict__ a_dst){
  int id = blockIdx.x*256 + threadIdx.x;
  if(id >= N_NODES*H1) return;
  int n = id >> 3, h = id & 7;
  const float* row = h1 + (size_t)n*F1 + h*16;
  float s1=0.f, s2=0.f;
  #pragma unroll
  for(int c=0;c<16;c++){
    float v = row[c];
    s1 += v * as_w[h*16+c];
    s2 += v * ad_w[h*16+c];
  }
  a_src[id]=s1; a_dst[id]=s2;
}

// ---------------- edge weights layer 1: w = exp(leaky(a_src[s]+a_dst[d])) ----------------

__global__ __launch_bounds__(256) void k_edgew1(const int* __restrict__ src_sorted, const int* __restrict__ dst_sorted,
                                                const float* __restrict__ a_src, const float* __restrict__ a_dst,
                                                float* __restrict__ w1s){
  int id = blockIdx.x*256 + threadIdx.x;
  if(id >= ETOT*H1) return;
  int i = id >> 3, h = id & 7;
  int s = src_sorted[i], d = dst_sorted[i];
  float e = a_src[s*H1 + h] + a_dst[d*H1 + h];
  e = e > 0.f ? e : 0.2f*e;
  w1s[id] = __expf(e);
}

// ---------------- layer-1 aggregation (precomputed w) + ELU(out+b1) ----------------

__global__ __launch_bounds__(256) void k_agg1(const float* __restrict__ h1, const float* __restrict__ w1s,
                                              const int* __restrict__ row_ptr, const int* __restrict__ src_sorted,
                                              const float* __restrict__ b1, float* __restrict__ g){
  int wave = threadIdx.x >> 6, lane = threadIdx.x & 63;
  int n = blockIdx.x*4 + wave;
  if(n >= N_NODES) return;
  int hl = lane >> 3;
  float wsum = 0.f, accx = 0.f, accy = 0.f;
  int rs = row_ptr[n], re = row_ptr[n+1];
  const float2* h12 = (const float2*)h1;
  for(int base=rs; base<re; base+=64){
    int idx = base + lane;
    int sv = (idx < re) ? src_sorted[idx] : 0;
    int cnt = min(64, re - base);
    for(int j=0;j<cnt;j++){
      int s = __shfl(sv, j);
      float w = w1s[(size_t)(base+j)*H1 + hl];
      float2 hv = h12[(size_t)s*64 + lane];
      accx += w*hv.x;
      accy += w*hv.y;
      wsum += w;
    }
  }
  float inv = 1.f/(wsum + 1e-16f);
  int c0 = lane*2;
  float o0 = accx*inv + b1[c0];
  float o1 = accy*inv + b1[c0+1];
  o0 = o0 > 0.f ? o0 : expm1f(o0);
  o1 = o1 > 0.f ? o1 : expm1f(o1);
  *(float2*)(g + (size_t)n*F1 + c0) = make_float2(o0,o1);
}

// ---------------- GEMM2: h2 = g @ W2  (50000x128 @ 128x40) ----------------

__global__ __launch_bounds__(256) void k_gemm2(const float* __restrict__ g, const float* __restrict__ W2,
                                               float* __restrict__ h2){
  __shared__ float Ws[128*40];
  __shared__ float Gs[32][128];
  int tid = threadIdx.x;
  for(int i=tid; i<128*40; i+=256) Ws[i] = W2[i];
  int r0 = blockIdx.x*32;
  #pragma unroll
  for(int q=0;q<4;q++){
    int slot = tid + q*256;
    int r = slot>>5, c4 = slot&31;
    int gr = r0 + r;
    float4 v = (gr < N_NODES) ? *(const float4*)(g + (size_t)gr*F1 + c4*4)
                              : make_float4(0.f,0.f,0.f,0.f);
    *(float4*)&Gs[r][c4*4] = v;
  }
  __syncthreads();
  #pragma unroll
  for(int q=0;q<5;q++){
    int o = q*256 + tid;
    int r = o/40, c = o - r*40;
    if(r0 + r < N_NODES){
      float acc = 0.f;
      #pragma unroll 4
      for(int k=0;k<128;k++) acc += Gs[r][k]*Ws[k*40+c];
      h2[(size_t)(r0+r)*F2 + c] = acc;
    }
  }
}

// ---------------- attention scores layer 2 ----------------

__global__ __launch_bounds__(256) void k_att2(const float* __restrict__ h2, const float* __restrict__ as_w,
                                              const float* __restrict__ ad_w,
                                              float* __restrict__ a_src, float* __restrict__ a_dst){
  int n = blockIdx.x*256 + threadIdx.x;
  if(n >= N_NODES) return;
  float s1=0.f, s2=0.f;
  #pragma unroll
  for(int c=0;c<F2;c++){
    float v = h2[(size_t)n*F2 + c];
    s1 += v * as_w[c];
    s2 += v * ad_w[c];
  }
  a_src[n]=s1; a_dst[n]=s2;
}

// ---------------- edge weights layer 2 ----------------

__global__ __launch_bounds__(256) void k_edgew2(const int* __restrict__ src_sorted, const int* __restrict__ dst_sorted,
                                                const float* __restrict__ a_src, const float* __restrict__ a_dst,
                                                float* __restrict__ w2s){
  int i = blockIdx.x*256 + threadIdx.x;
  if(i >= ETOT) return;
  float e = a_src[src_sorted[i]] + a_dst[dst_sorted[i]];
  e = e > 0.f ? e : 0.2f*e;
  w2s[i] = __expf(e);
}

// ---------------- layer-2 aggregation + bias + log_softmax ----------------

__global__ __launch_bounds__(256) void k_agg2(const float* __restrict__ h2, const float* __restrict__ w2s,
                                              const int* __restrict__ row_ptr, const int* __restrict__ src_sorted,
                                              const float* __restrict__ b2, float* __restrict__ out){
  int wave = threadIdx.x >> 6, lane = threadIdx.x & 63;
  int n = blockIdx.x*4 + wave;
  if(n >= N_NODES) return;
  float wsum = 0.f, acc = 0.f;
  int c = (lane < F2) ? lane : (F2-1);
  int rs = row_ptr[n], re = row_ptr[n+1];
  for(int base=rs; base<re; base+=64){
    int idx = base + lane;
    int sv = (idx < re) ? src_sorted[idx] : 0;
    int cnt = min(64, re - base);
    for(int j=0;j<cnt;j++){
      int s = __shfl(sv, j);
      float w = w2s[base+j];
      acc += w*h2[(size_t)s*F2 + c];
      wsum += w;
    }
  }
  float v = acc/(wsum + 1e-16f) + b2[c];
  float mv = (lane < F2) ? v : -INFINITY;
  #pragma unroll
  for(int off=32; off; off>>=1) mv = fmaxf(mv, __shfl_xor(mv, off));
  float ex = (lane < F2) ? __expf(v - mv) : 0.f;
  #pragma unroll
  for(int off=32; off; off>>=1) ex += __shfl_xor(ex, off);
  if(lane < F2) out[(size_t)n*F2 + lane] = v - mv - logf(ex);
}

// ---------------- launcher ----------------

extern "C" void kernel_launch(void* const* d_in, const int* in_sizes, int n_in,
                              void* d_out, int out_size, void* d_ws, size_t ws_size,
                              hipStream_t stream) {
  const float* x        = (const float*)d_in[0];
  const int*   eidx     = (const int*)d_in[1];
  const float* W1       = (const float*)d_in[2];
  const float* att_src1 = (const float*)d_in[3];
  const float* att_dst1 = (const float*)d_in[4];
  const float* b1       = (const float*)d_in[5];
  const float* W2       = (const float*)d_in[6];
  const float* att_src2 = (const float*)d_in[7];
  const float* att_dst2 = (const float*)d_in[8];
  const float* b2       = (const float*)d_in[9];
  float* out = (float*)d_out;

  const int* src = eidx;
  const int* dst = eidx + NE;

  // workspace layout
  float* h1     = (float*)d_ws;                       // 6,400,000
  float* g      = h1 + 6400000;                       // 6,400,000
  float* h2     = g  + 6400000;                       // 2,000,000
  float* a_src1 = h2 + 2000000;                       // 400,000
  float* a_dst1 = a_src1 + 400000;                    // 400,000
  float* a_src2 = a_dst1 + 400000;                    // 50,000
  float* a_dst2 = a_src2 + 50000;                     // 50,000
  int* row_ptr  = (int*)(a_dst2 + 50000);             // 50,001 (+pad)
  int* cursor   = row_ptr + 50002;                    // 50,000 (+pad)
  int* partials = cursor + 50002;                     // 256
  int* src_sorted = partials + 256;                   // 850,000
  int* dst_sorted = src_sorted + 850000;              // 850,000
  float* w1s    = (float*)(dst_sorted + 850000);      // 6,800,000
  float* w2s    = w1s + (size_t)ETOT*H1;              // 850,000
  ushort* Wtb   = (ushort*)(w2s + 850000);            // 65,536 bf16

  const int SCAN_BLOCKS = (N_NODES + 255)/256;

  // CSR build (cursor doubles as deg buffer)
  hipMemsetAsync(cursor, 0, (size_t)N_NODES*sizeof(int), stream);
  k_hist   <<<(ETOT+255)/256, 256, 0, stream>>>(dst, cursor);
  k_scan1  <<<SCAN_BLOCKS, 256, 0, stream>>>(cursor, row_ptr, partials);
  k_scan2  <<<1, 256, 0, stream>>>(partials, SCAN_BLOCKS);
  k_scan3  <<<SCAN_BLOCKS, 256, 0, stream>>>(row_ptr, partials, cursor);
  k_scatter<<<(ETOT+255)/256, 256, 0, stream>>>(src, dst, cursor, src_sorted, dst_sorted);

  // layer 1
  k_cvtW  <<<(FIN*F1+255)/256, 256, 0, stream>>>(W1, Wtb);
  k_gemm1 <<<(N_NODES+31)/32, 256, 0, stream>>>(x, Wtb, h1);
  k_att1  <<<(N_NODES*H1+255)/256, 256, 0, stream>>>(h1, att_src1, att_dst1, a_src1, a_dst1);
  k_edgew1<<<((size_t)ETOT*H1+255)/256, 256, 0, stream>>>(src_sorted, dst_sorted, a_src1, a_dst1, w1s);
  k_agg1  <<<(N_NODES+3)/4, 256, 0, stream>>>(h1, w1s, row_ptr, src_sorted, b1, g);

  // layer 2
  k_gemm2 <<<(N_NODES+31)/32, 256, 0, stream>>>(g, W2, h2);
  k_att2  <<<(N_NODES+255)/256, 256, 0, stream>>>(h2, att_src2, att_dst2, a_src2, a_dst2);
  k_edgew2<<<(ETOT+255)/256, 256, 0, stream>>>(src_sorted, dst_sorted, a_src2, a_dst2, w2s);
  k_agg2  <<<(N_NODES+3)/4, 256, 0, stream>>>(h2, w2s, row_ptr, src_sorted, b2, out);
}

// Round 5
// 425.844 us; speedup vs baseline: 1.2399x; 1.1296x over previous
//
#include <hip/hip_runtime.h>
#include <math.h>

#define N_NODES 50000
#define FIN 512
#define NE 800000
#define ETOT 850000   // NE + N_NODES self loops
#define F1 128        // H1*C1
#define H1 8
#define F2 40

typedef __attribute__((ext_vector_type(8))) short bf16x8;
typedef __attribute__((ext_vector_type(4))) float f32x4;

__device__ inline ushort f2bf(float f){
  union{float f; unsigned u;} v; v.f=f;
  return (ushort)((v.u + 0x8000u) >> 16);
}
__device__ inline float bflo(uint u){ union{uint a;float f;} v; v.a = u << 16;         return v.f; }
__device__ inline float bfhi(uint u){ union{uint a;float f;} v; v.a = u & 0xffff0000u; return v.f; }
__device__ inline float bf1(ushort u){ union{uint a;float f;} v; v.a = ((uint)u) << 16; return v.f; }

// ---------------- CSR build ----------------

__global__ __launch_bounds__(256) void k_hist(const int* __restrict__ dst, int* __restrict__ deg){
  int i = blockIdx.x*256 + threadIdx.x;
  if(i < ETOT){
    int d = (i < NE) ? dst[i] : (i - NE);
    atomicAdd(&deg[d], 1);
  }
}

__global__ __launch_bounds__(256) void k_scan1(const int* __restrict__ deg, int* __restrict__ row_ptr,
                                               int* __restrict__ partials){
  __shared__ int sm[256];
  int t = threadIdx.x;
  int i = blockIdx.x*256 + t;
  int v = (i < N_NODES) ? deg[i] : 0;
  sm[t] = v;
  __syncthreads();
  for(int off=1; off<256; off<<=1){
    int x = (t >= off) ? sm[t-off] : 0;
    __syncthreads();
    sm[t] += x;
    __syncthreads();
  }
  if(i < N_NODES) row_ptr[i] = sm[t] - v;
  if(t == 255) partials[blockIdx.x] = sm[255];
}

__global__ __launch_bounds__(256) void k_scan2(int* __restrict__ partials, int nblocks){
  __shared__ int sm[256];
  int t = threadIdx.x;
  int v = (t < nblocks) ? partials[t] : 0;
  sm[t] = v;
  __syncthreads();
  for(int off=1; off<256; off<<=1){
    int x = (t >= off) ? sm[t-off] : 0;
    __syncthreads();
    sm[t] += x;
    __syncthreads();
  }
  if(t < nblocks) partials[t] = sm[t] - v;
}

__global__ __launch_bounds__(256) void k_scan3(int* __restrict__ row_ptr, const int* __restrict__ partials,
                                               int* __restrict__ cursor){
  int i = blockIdx.x*256 + threadIdx.x;
  if(i < N_NODES){
    int rp = row_ptr[i] + partials[blockIdx.x];
    row_ptr[i] = rp;
    cursor[i]  = rp;
  }
  if(i == 0) row_ptr[N_NODES] = ETOT;
}

__global__ __launch_bounds__(256) void k_scatter(const int* __restrict__ src, const int* __restrict__ dst,
                                                 int* __restrict__ cursor,
                                                 int* __restrict__ src_sorted, int* __restrict__ dst_sorted){
  int i = blockIdx.x*256 + threadIdx.x;
  if(i < ETOT){
    int d, s;
    if(i < NE){ d = dst[i]; s = src[i]; }
    else      { d = i - NE; s = i - NE; }
    int pos = atomicAdd(&cursor[d], 1);
    src_sorted[pos] = s;
    dst_sorted[pos] = d;
  }
}

// ---------------- W1 convert to frag-blocked layout ----------------

__global__ __launch_bounds__(256) void k_cvtW(const float* __restrict__ W, ushort* __restrict__ Wtb){
  int id = blockIdx.x*256 + threadIdx.x;    // 65536
  int k = id >> 7, n = id & 127;
  Wtb[(size_t)(k>>3)*1024 + n*8 + (k&7)] = f2bf(W[id]);
}

// ---------------- GEMM1 (bf16 MFMA): h1b = bf16(x @ W1) ----------------

__global__ __launch_bounds__(256) void k_gemm1(const float* __restrict__ x, const ushort* __restrict__ Wtb,
                                               ushort* __restrict__ h1b){
  __shared__ ushort Asm[2][32][40];
  int tid  = threadIdx.x;
  int wave = tid >> 6, lane = tid & 63;
  int l15 = lane & 15, quad = lane >> 4;
  int bx = blockIdx.x;

  f32x4 acc[2][2];
  #pragma unroll
  for(int i=0;i<2;i++)
    #pragma unroll
    for(int j=0;j<2;j++) acc[i][j] = (f32x4){0.f,0.f,0.f,0.f};

  int am  = tid >> 3;
  int ak4 = (tid & 7) << 2;
  int agr = bx*32 + am;
  bool aok = agr < N_NODES;
  const float* xrow = x + (size_t)agr*FIN + ak4;

  {
    float4 a0 = aok ? *(const float4*)xrow : make_float4(0,0,0,0);
    ushort4 p = make_ushort4(f2bf(a0.x),f2bf(a0.y),f2bf(a0.z),f2bf(a0.w));
    *(ushort4*)&Asm[0][am][ak4] = p;
  }

  const ushort* wp[2];
  #pragma unroll
  for(int tn=0;tn<2;tn++)
    wp[tn] = Wtb + (size_t)quad*1024 + (size_t)(wave*32 + tn*16 + l15)*8;

  bf16x8 bcur[2];
  bcur[0] = *(const bf16x8*)wp[0];
  bcur[1] = *(const bf16x8*)wp[1];
  __syncthreads();

  for(int kt=0; kt<FIN; kt+=32){
    int cur = (kt >> 5) & 1;
    bool hn = (kt + 32) < FIN;

    float4 an = make_float4(0,0,0,0);
    if(hn && aok) an = *(const float4*)(xrow + kt + 32);

    bf16x8 bnext[2];
    if(hn){
      bnext[0] = *(const bf16x8*)(wp[0] + (size_t)(kt+32)*128);
      bnext[1] = *(const bf16x8*)(wp[1] + (size_t)(kt+32)*128);
    }

    bf16x8 af[2];
    af[0] = *(bf16x8*)&Asm[cur][l15][quad*8];
    af[1] = *(bf16x8*)&Asm[cur][16+l15][quad*8];

    #pragma unroll
    for(int tm=0;tm<2;tm++)
      #pragma unroll
      for(int tn=0;tn<2;tn++)
        acc[tm][tn] = __builtin_amdgcn_mfma_f32_16x16x32_bf16(af[tm], bcur[tn], acc[tm][tn], 0,0,0);

    if(hn){
      ushort4 p = make_ushort4(f2bf(an.x),f2bf(an.y),f2bf(an.z),f2bf(an.w));
      *(ushort4*)&Asm[cur^1][am][ak4] = p;
    }
    __syncthreads();
    bcur[0] = bnext[0];
    bcur[1] = bnext[1];
  }

  #pragma unroll
  for(int tm=0;tm<2;tm++){
    #pragma unroll
    for(int r=0;r<4;r++){
      int row = bx*32 + tm*16 + quad*4 + r;
      if(row < N_NODES){
        #pragma unroll
        for(int tn=0;tn<2;tn++){
          int col = wave*32 + tn*16 + l15;
          h1b[(size_t)row*F1 + col] = f2bf(acc[tm][tn][r]);
        }
      }
    }
  }
}

// ---------------- attention scores layer 1 (bf16 input) ----------------

__global__ __launch_bounds__(256) void k_att1(const ushort* __restrict__ h1b, const float* __restrict__ as_w,
                                              const float* __restrict__ ad_w,
                                              float* __restrict__ a_src, float* __restrict__ a_dst){
  int id = blockIdx.x*256 + threadIdx.x;
  if(id >= N_NODES*H1) return;
  int n = id >> 3, h = id & 7;
  const uint* rp = (const uint*)(h1b + (size_t)n*F1 + h*16);
  float s1=0.f, s2=0.f;
  #pragma unroll
  for(int q=0;q<8;q++){
    uint u = rp[q];
    float v0 = bflo(u), v1 = bfhi(u);
    s1 += v0 * as_w[h*16+q*2]   + v1 * as_w[h*16+q*2+1];
    s2 += v0 * ad_w[h*16+q*2]   + v1 * ad_w[h*16+q*2+1];
  }
  a_src[id]=s1; a_dst[id]=s2;
}

// ---------------- edge weights layer 1 ----------------

__global__ __launch_bounds__(256) void k_edgew1(const int* __restrict__ src_sorted, const int* __restrict__ dst_sorted,
                                                const float* __restrict__ a_src, const float* __restrict__ a_dst,
                                                float* __restrict__ w1s){
  int id = blockIdx.x*256 + threadIdx.x;
  if(id >= ETOT*H1) return;
  int i = id >> 3, h = id & 7;
  int s = src_sorted[i], d = dst_sorted[i];
  float e = a_src[s*H1 + h] + a_dst[d*H1 + h];
  e = e > 0.f ? e : 0.2f*e;
  w1s[id] = __expf(e);
}

// ---------------- layer-1 aggregation (bf16 gather, 2-way MLP) + ELU ----------------

__global__ __launch_bounds__(256) void k_agg1(const ushort* __restrict__ h1b, const float* __restrict__ w1s,
                                              const int* __restrict__ row_ptr, const int* __restrict__ src_sorted,
                                              const float* __restrict__ b1, float* __restrict__ g){
  int wave = threadIdx.x >> 6, lane = threadIdx.x & 63;
  int n = blockIdx.x*4 + wave;
  if(n >= N_NODES) return;
  int hl = lane >> 3;
  float wsum0=0.f, accx0=0.f, accy0=0.f;
  float wsum1=0.f, accx1=0.f, accy1=0.f;
  int rs = row_ptr[n], re = row_ptr[n+1];
  const uint* h1u = (const uint*)h1b;   // lane covers channels 2*lane, 2*lane+1
  for(int base=rs; base<re; base+=64){
    int idx = base + lane;
    int sv = (idx < re) ? src_sorted[idx] : 0;
    int cnt = min(64, re - base);
    int j = 0;
    for(; j+1<cnt; j+=2){
      int s0 = __shfl(sv, j), s1 = __shfl(sv, j+1);
      float w0 = w1s[(size_t)(base+j)*H1 + hl];
      float w1 = w1s[(size_t)(base+j+1)*H1 + hl];
      uint u0 = h1u[(size_t)s0*64 + lane];
      uint u1 = h1u[(size_t)s1*64 + lane];
      accx0 += w0*bflo(u0); accy0 += w0*bfhi(u0); wsum0 += w0;
      accx1 += w1*bflo(u1); accy1 += w1*bfhi(u1); wsum1 += w1;
    }
    if(j < cnt){
      int s0 = __shfl(sv, j);
      float w0 = w1s[(size_t)(base+j)*H1 + hl];
      uint u0 = h1u[(size_t)s0*64 + lane];
      accx0 += w0*bflo(u0); accy0 += w0*bfhi(u0); wsum0 += w0;
    }
  }
  float inv = 1.f/((wsum0+wsum1) + 1e-16f);
  int c0 = lane*2;
  float o0 = (accx0+accx1)*inv + b1[c0];
  float o1 = (accy0+accy1)*inv + b1[c0+1];
  o0 = o0 > 0.f ? o0 : expm1f(o0);
  o1 = o1 > 0.f ? o1 : expm1f(o1);
  *(float2*)(g + (size_t)n*F1 + c0) = make_float2(o0,o1);
}

// ---------------- GEMM2: h2b = bf16(g @ W2)  (50000x128 @ 128x40) ----------------

__global__ __launch_bounds__(256) void k_gemm2(const float* __restrict__ g, const float* __restrict__ W2,
                                               ushort* __restrict__ h2b){
  __shared__ float Ws[128*40];
  __shared__ float Gs[32][128];
  int tid = threadIdx.x;
  for(int i=tid; i<128*40; i+=256) Ws[i] = W2[i];
  int r0 = blockIdx.x*32;
  #pragma unroll
  for(int q=0;q<4;q++){
    int slot = tid + q*256;
    int r = slot>>5, c4 = slot&31;
    int gr = r0 + r;
    float4 v = (gr < N_NODES) ? *(const float4*)(g + (size_t)gr*F1 + c4*4)
                              : make_float4(0.f,0.f,0.f,0.f);
    *(float4*)&Gs[r][c4*4] = v;
  }
  __syncthreads();
  #pragma unroll
  for(int q=0;q<5;q++){
    int o = q*256 + tid;
    int r = o/40, c = o - r*40;
    if(r0 + r < N_NODES){
      float acc = 0.f;
      #pragma unroll 4
      for(int k=0;k<128;k++) acc += Gs[r][k]*Ws[k*40+c];
      h2b[(size_t)(r0+r)*F2 + c] = f2bf(acc);
    }
  }
}

// ---------------- attention scores layer 2 (bf16 input) ----------------

__global__ __launch_bounds__(256) void k_att2(const ushort* __restrict__ h2b, const float* __restrict__ as_w,
                                              const float* __restrict__ ad_w,
                                              float* __restrict__ a_src, float* __restrict__ a_dst){
  int n = blockIdx.x*256 + threadIdx.x;
  if(n >= N_NODES) return;
  const uint* rp = (const uint*)(h2b + (size_t)n*F2);
  float s1=0.f, s2=0.f;
  #pragma unroll
  for(int q=0;q<20;q++){
    uint u = rp[q];
    float v0 = bflo(u), v1 = bfhi(u);
    s1 += v0 * as_w[q*2] + v1 * as_w[q*2+1];
    s2 += v0 * ad_w[q*2] + v1 * ad_w[q*2+1];
  }
  a_src[n]=s1; a_dst[n]=s2;
}

// ---------------- edge weights layer 2 ----------------

__global__ __launch_bounds__(256) void k_edgew2(const int* __restrict__ src_sorted, const int* __restrict__ dst_sorted,
                                                const float* __restrict__ a_src, const float* __restrict__ a_dst,
                                                float* __restrict__ w2s){
  int i = blockIdx.x*256 + threadIdx.x;
  if(i >= ETOT) return;
  float e = a_src[src_sorted[i]] + a_dst[dst_sorted[i]];
  e = e > 0.f ? e : 0.2f*e;
  w2s[i] = __expf(e);
}

// ---------------- layer-2 aggregation (bf16 gather, 2-way MLP) + log_softmax ----------------

__global__ __launch_bounds__(256) void k_agg2(const ushort* __restrict__ h2b, const float* __restrict__ w2s,
                                              const int* __restrict__ row_ptr, const int* __restrict__ src_sorted,
                                              const float* __restrict__ b2, float* __restrict__ out){
  int wave = threadIdx.x >> 6, lane = threadIdx.x & 63;
  int n = blockIdx.x*4 + wave;
  if(n >= N_NODES) return;
  float wsum0=0.f, acc0=0.f, wsum1=0.f, acc1=0.f;
  int c = (lane < F2) ? lane : (F2-1);
  int rs = row_ptr[n], re = row_ptr[n+1];
  for(int base=rs; base<re; base+=64){
    int idx = base + lane;
    int sv = (idx < re) ? src_sorted[idx] : 0;
    int cnt = min(64, re - base);
    int j = 0;
    for(; j+1<cnt; j+=2){
      int s0 = __shfl(sv, j), s1 = __shfl(sv, j+1);
      float w0 = w2s[base+j], w1 = w2s[base+j+1];
      float v0 = bf1(h2b[(size_t)s0*F2 + c]);
      float v1 = bf1(h2b[(size_t)s1*F2 + c]);
      acc0 += w0*v0; wsum0 += w0;
      acc1 += w1*v1; wsum1 += w1;
    }
    if(j < cnt){
      int s0 = __shfl(sv, j);
      float w0 = w2s[base+j];
      acc0 += w0*bf1(h2b[(size_t)s0*F2 + c]); wsum0 += w0;
    }
  }
  float v = (acc0+acc1)/((wsum0+wsum1) + 1e-16f) + b2[c];
  float mv = (lane < F2) ? v : -INFINITY;
  #pragma unroll
  for(int off=32; off; off>>=1) mv = fmaxf(mv, __shfl_xor(mv, off));
  float ex = (lane < F2) ? __expf(v - mv) : 0.f;
  #pragma unroll
  for(int off=32; off; off>>=1) ex += __shfl_xor(ex, off);
  if(lane < F2) out[(size_t)n*F2 + lane] = v - mv - logf(ex);
}

// ---------------- launcher ----------------

extern "C" void kernel_launch(void* const* d_in, const int* in_sizes, int n_in,
                              void* d_out, int out_size, void* d_ws, size_t ws_size,
                              hipStream_t stream) {
  const float* x        = (const float*)d_in[0];
  const int*   eidx     = (const int*)d_in[1];
  const float* W1       = (const float*)d_in[2];
  const float* att_src1 = (const float*)d_in[3];
  const float* att_dst1 = (const float*)d_in[4];
  const float* b1       = (const float*)d_in[5];
  const float* W2       = (const float*)d_in[6];
  const float* att_src2 = (const float*)d_in[7];
  const float* att_dst2 = (const float*)d_in[8];
  const float* b2       = (const float*)d_in[9];
  float* out = (float*)d_out;

  const int* src = eidx;
  const int* dst = eidx + NE;

  // workspace layout
  ushort* h1b  = (ushort*)d_ws;                       // 6,400,000 ushort
  ushort* h2b  = h1b + 6400000;                       // 2,000,000
  ushort* Wtb  = h2b + 2000000;                       // 65,536
  float* g     = (float*)(Wtb + 65536);               // 6,400,000 f
  float* a_src1 = g + 6400000;                        // 400,000
  float* a_dst1 = a_src1 + 400000;                    // 400,000
  float* a_src2 = a_dst1 + 400000;                    // 50,000
  float* a_dst2 = a_src2 + 50000;                     // 50,000
  float* w1s    = a_dst2 + 50000;                     // 6,800,000
  float* w2s    = w1s + (size_t)ETOT*H1;              // 850,000
  int* row_ptr  = (int*)(w2s + 850000);               // 50,002
  int* cursor   = row_ptr + 50002;                    // 50,002
  int* partials = cursor + 50002;                     // 256
  int* src_sorted = partials + 256;                   // 850,000
  int* dst_sorted = src_sorted + 850000;              // 850,000

  const int SCAN_BLOCKS = (N_NODES + 255)/256;

  // CSR build (cursor doubles as deg buffer)
  hipMemsetAsync(cursor, 0, (size_t)N_NODES*sizeof(int), stream);
  k_hist   <<<(ETOT+255)/256, 256, 0, stream>>>(dst, cursor);
  k_scan1  <<<SCAN_BLOCKS, 256, 0, stream>>>(cursor, row_ptr, partials);
  k_scan2  <<<1, 256, 0, stream>>>(partials, SCAN_BLOCKS);
  k_scan3  <<<SCAN_BLOCKS, 256, 0, stream>>>(row_ptr, partials, cursor);
  k_scatter<<<(ETOT+255)/256, 256, 0, stream>>>(src, dst, cursor, src_sorted, dst_sorted);

  // layer 1
  k_cvtW  <<<(FIN*F1+255)/256, 256, 0, stream>>>(W1, Wtb);
  k_gemm1 <<<(N_NODES+31)/32, 256, 0, stream>>>(x, Wtb, h1b);
  k_att1  <<<(N_NODES*H1+255)/256, 256, 0, stream>>>(h1b, att_src1, att_dst1, a_src1, a_dst1);
  k_edgew1<<<((size_t)ETOT*H1+255)/256, 256, 0, stream>>>(src_sorted, dst_sorted, a_src1, a_dst1, w1s);
  k_agg1  <<<(N_NODES+3)/4, 256, 0, stream>>>(h1b, w1s, row_ptr, src_sorted, b1, g);

  // layer 2
  k_gemm2 <<<(N_NODES+31)/32, 256, 0, stream>>>(g, W2, h2b);
  k_att2  <<<(N_NODES+255)/256, 256, 0, stream>>>(h2b, att_src2, att_dst2, a_src2, a_dst2);
  k_edgew2<<<(ETOT+255)/256, 256, 0, stream>>>(src_sorted, dst_sorted, a_src2, a_dst2, w2s);
  k_agg2  <<<(N_NODES+3)/4, 256, 0, stream>>>(h2b, w2s, row_ptr, src_sorted, b2, out);
}